// Round 5
// baseline (16.379 us; speedup 1.0000x reference)
//
#include <hip/hip_runtime.h>

// Problem constants (from reference)
#define N_ 16
#define A_ 4096
#define G_ 256
#define C_ 80
#define BIG_ 1e8f
#define LN2_ 0.69314718055994531f

// Block = 256 threads = 4 waves; each wave owns 16 anchors, 4 passes x 4
// anchors (one per 16-lane group). Each lane register-caches 16 gt boxes
// (g = sub + 16*m) -> hot argmin loop has ZERO LDS/global traffic.
// Latency structure (the round-5 point):
//  - no dependent global loads: x_target selected from the already-loaded
//    xv[] registers via a static cndmask chain
//  - (d,idx) argmin reduced as ONE u64 min (bits(d)<<32 | g): 4 shuffle
//    stages instead of 8, exact first-occurrence jnp.argmin semantics
//  - pass loop unrolled 2x so independent chains overlap
// Masked-out boxes staged as (BIG,BIG,BIG,BIG): distance ~4e8 never wins;
// nonempty <=> dmin < BIG; winner always masked-in.

__global__ __launch_bounds__(256) void cbppl_fused_kernel(
    const float* __restrict__ gt_padded,    // (N, G, 4)
    const float* __restrict__ prop_boxes,   // (N, A, 4)
    const float* __restrict__ pred_boxes,   // (N, A, 4)
    const float* __restrict__ class_logits, // (N, A, C)
    const int*   __restrict__ gt_masks,     // (N, G) bool->int32
    const int*   __restrict__ gt_classes,   // (N, G)
    float* __restrict__ out_cls,            // (N, A)
    float* __restrict__ out_proj)           // (N, A)
{
    __shared__ float4 s_gt[G_];
    __shared__ int    s_cls[G_];

    const int t   = threadIdx.x;
    const int sub = t & 15;                 // lane-in-group
    const int n   = blockIdx.x >> 6;        // 64 blocks per batch
    const int ab  = (blockIdx.x & 63) << 6; // 64 anchors per block

    // ---- one-time: stage masked gt boxes + classes to LDS ----
    {
        const int gidx = n * G_ + t;        // t == g (256 threads)
        float4 g4 = ((const float4*)gt_padded)[gidx];
        if (!gt_masks[gidx]) { g4.x = BIG_; g4.y = BIG_; g4.z = BIG_; g4.w = BIG_; }
        s_gt[t]  = g4;
        s_cls[t] = gt_classes[gidx];
    }
    __syncthreads();

    // ---- one-time: register-cache 16 boxes per lane (interleaved) ----
    float4 b[16];
    #pragma unroll
    for (int m = 0; m < 16; ++m) b[m] = s_gt[sub + (m << 4)];

    // ---- 4 passes, unrolled 2x for cross-pass latency overlap ----
    #pragma unroll 2
    for (int p = 0; p < 4; ++p) {
        const int ai  = ((t >> 6) << 4) + (p << 2) + ((t >> 4) & 3);
        const int row = n * A_ + ab + ai;

        const float4 pb = ((const float4*)prop_boxes)[row];   // group-broadcast
        const float4 qb = ((const float4*)pred_boxes)[row];

        // 5 logit loads issued early (independent of argmin)
        const float* lrow = class_logits + (size_t)row * C_;
        float xv[5];
        #pragma unroll
        for (int k = 0; k < 5; ++k) xv[k] = lrow[sub + (k << 4)];

        // local argmin over 16 register boxes, two chains for ILP
        float d0 = INFINITY, d1 = INFINITY;
        int   m0 = 0,        m1 = 1;
        #pragma unroll
        for (int m = 0; m < 16; m += 2) {
            const float4 ba = b[m];
            const float da = fabsf(pb.x - ba.x) + fabsf(pb.y - ba.y)
                           + fabsf(pb.z - ba.z) + fabsf(pb.w - ba.w);
            if (da < d0) { d0 = da; m0 = m; }
            const float4 bb = b[m + 1];
            const float db = fabsf(pb.x - bb.x) + fabsf(pb.y - bb.y)
                           + fabsf(pb.z - bb.z) + fabsf(pb.w - bb.w);
            if (db < d1) { d1 = db; m1 = m + 1; }
        }
        float dloc = d0; int mloc = m0;
        if (d1 < d0 || (d1 == d0 && m1 < m0)) { dloc = d1; mloc = m1; }
        const int iloc = (mloc << 4) + sub;   // g index

        // 16-lane argmin as ONE u64 min: (bits(d)<<32)|g, d>=0 => monotonic
        unsigned long long key =
            ((unsigned long long)__float_as_uint(dloc) << 32) | (unsigned)iloc;
        #pragma unroll
        for (int k = 1; k < 16; k <<= 1) {
            const unsigned long long o = __shfl_xor(key, k, 64);
            key = (o < key) ? o : key;
        }
        const int   closest = (int)(key & 0xFFFFFFFFull);
        const float dmin    = __uint_as_float((unsigned)(key >> 32));
        const int   nonempty = (dmin < BIG_);

        // epilogue lookups: uniform per group -> LDS broadcast
        const float4 cb     = s_gt[closest];
        const int    target = s_cls[closest];
        const float  pd = fabsf(qb.x - cb.x) + fabsf(qb.y - cb.y)
                        + fabsf(qb.z - cb.z) + fabsf(qb.w - cb.w);

        // focal loss, negative-class closed form: 0.75 * softplus(x) * p^2
        float acc = 0.0f;
        #pragma unroll
        for (int k = 0; k < 5; ++k) {
            const float x  = xv[k];
            const float e  = __expf(-fabsf(x));
            const float tt = 1.0f + e;
            const float sp = fmaf(LN2_, __log2f(tt), fmaxf(x, 0.0f)); // softplus(x)
            const float r  = __builtin_amdgcn_rcpf(tt);
            const float pp = (x >= 0.0f) ? r : e * r;                 // sigmoid(x)
            acc += sp * pp * pp;
        }
        acc *= 0.75f;

        // target-class correction — x_target selected FROM REGISTERS
        // (kt group-uniform; static indices only)
        {
            const int kt = target >> 4;
            float xt = xv[0];
            xt = (kt == 1) ? xv[1] : xt;
            xt = (kt == 2) ? xv[2] : xt;
            xt = (kt == 3) ? xv[3] : xt;
            xt = (kt == 4) ? xv[4] : xt;
            const float e  = __expf(-fabsf(xt));
            const float tt = 1.0f + e;
            const float sp = fmaf(LN2_, __log2f(tt), fmaxf(xt, 0.0f));
            const float r  = __builtin_amdgcn_rcpf(tt);
            const float pp = (xt >= 0.0f) ? r : e * r;
            const float q  = 1.0f - pp;
            const float corr = 0.25f * (sp - xt) * q * q - 0.75f * sp * pp * pp;
            acc += ((target & 15) == sub) ? corr : 0.0f;  // only owner lane adds
        }

        // group sum of focal partials
        #pragma unroll
        for (int k = 1; k < 16; k <<= 1) acc += __shfl_xor(acc, k, 64);

        if (sub == 0) {
            out_cls[row]  = nonempty ? acc * (1.0f / (float)C_) : 0.0f;
            out_proj[row] = nonempty ? pd : 0.0f;
        }
    }
}

extern "C" void kernel_launch(void* const* d_in, const int* in_sizes, int n_in,
                              void* d_out, int out_size, void* d_ws, size_t ws_size,
                              hipStream_t stream) {
    const float* gt_padded    = (const float*)d_in[0];
    const float* prop_boxes   = (const float*)d_in[1];
    const float* pred_boxes   = (const float*)d_in[2];
    const float* class_logits = (const float*)d_in[3];
    const int*   gt_masks     = (const int*)d_in[4];
    const int*   gt_classes   = (const int*)d_in[5];

    float* out = (float*)d_out;
    float* out_cls  = out;             // classification_loss, (N, A)
    float* out_proj = out + N_ * A_;   // projection_loss,     (N, A)

    dim3 grid(N_ * A_ / 64);           // 1024 blocks, 64 anchors each
    dim3 block(256);
    cbppl_fused_kernel<<<grid, block, 0, stream>>>(
        gt_padded, prop_boxes, pred_boxes, class_logits,
        gt_masks, gt_classes, out_cls, out_proj);
}